// Round 1
// 1526.461 us; speedup vs baseline: 1.3294x; 1.3294x over previous
//
#include <hip/hip_runtime.h>
#include <hip/hip_bf16.h>
#include <cstdint>
#include <cstddef>

// Problem constants (match reference)
#define Hdim 1024
#define Vdim 32000
#define LAYERS 3
#define Bdim 64
#define Tdim 32
#define BT 2048      // B*T
#define G3H 3072     // 3*H

using bf16 = __bf16;
using bf16x8 = __attribute__((ext_vector_type(8))) __bf16;  // one MFMA A/B fragment (4 VGPRs)
using bf16x4 = __attribute__((ext_vector_type(4))) __bf16;
using f32x4  = __attribute__((ext_vector_type(4))) float;

// async global->LDS, 16B per lane. LDS dest is wave-uniform base + lane*16.
typedef const __attribute__((address_space(1))) void* gas1_t;
typedef __attribute__((address_space(3))) void* las3_t;
__device__ __forceinline__ void g2lds16(const void* g, void* l) {
  __builtin_amdgcn_global_load_lds((gas1_t)g, (las3_t)l, 16, 0, 0);
}

// ---------------- fp32 -> bf16 conversion (weights) ----------------
__global__ __launch_bounds__(256) void cvt_f32_bf16(const float* __restrict__ src,
                                                    bf16* __restrict__ dst, int n4) {
  int i = blockIdx.x * 256 + threadIdx.x;
  if (i < n4) {
    f32x4 v = ((const f32x4*)src)[i];
    bf16x4 o;
    o[0] = (bf16)v[0]; o[1] = (bf16)v[1]; o[2] = (bf16)v[2]; o[3] = (bf16)v[3];
    ((bf16x4*)dst)[i] = o;
  }
}

// ---------------- embedding + relu -> bf16 x0 ----------------
__global__ __launch_bounds__(256) void embed_relu(const int* __restrict__ tgt,
                                                  const float* __restrict__ emb,
                                                  bf16* __restrict__ x) {
  int row = blockIdx.x;
  int b = row >> 5, t = row & 31;
  int id = (t == 0) ? 0 : tgt[b * Tdim + t - 1];
  const f32x4* src = (const f32x4*)(emb + (size_t)id * Hdim);
  bf16x4* dst = (bf16x4*)(x + (size_t)row * Hdim);
  f32x4 v = src[threadIdx.x];
  bf16x4 o;
  o[0] = (bf16)fmaxf(v[0], 0.f); o[1] = (bf16)fmaxf(v[1], 0.f);
  o[2] = (bf16)fmaxf(v[2], 0.f); o[3] = (bf16)fmaxf(v[3], 0.f);
  dst[threadIdx.x] = o;
}

// ---------------- hidden-state init from encoder_hidden[l] ----------------
__global__ __launch_bounds__(256) void hinit(const float* __restrict__ eh,
                                             float* __restrict__ h32,
                                             bf16* __restrict__ hbf) {
  int i = blockIdx.x * 256 + threadIdx.x;
  f32x4 v = ((const f32x4*)eh)[i];
  ((f32x4*)h32)[i] = v;
  bf16x4 o;
  o[0] = (bf16)v[0]; o[1] = (bf16)v[1]; o[2] = (bf16)v[2]; o[3] = (bf16)v[3];
  ((bf16x4*)hbf)[i] = o;
}

// ---------------- C = A @ B^T (+bias), LDS-staged (m97 structure) ----------------
// A: [M,K] bf16 row-major. Bm: [N,K] bf16 row-major. C: [M,N] fp32.
// Block 128x128 (4 waves, 64x64 each), BK=32, global_load_lds dwordx4 staging.
// Grid: blockIdx.x = M-tile (fast-varying -> consecutive blocks share B-tile),
//       blockIdx.y = N-tile.
template <bool BIAS>
__global__ __launch_bounds__(256) void gemm_lds(const bf16* __restrict__ A,
                                                const bf16* __restrict__ Bm,
                                                const float* __restrict__ bias,
                                                float* __restrict__ C,
                                                int M, int N, int K) {
  __shared__ bf16 As[128 * 32];   // 8 KB, row-major [128][32]
  __shared__ bf16 Bs[128 * 32];   // 8 KB

  int wave = threadIdx.x >> 6, lane = threadIdx.x & 63;
  int lane15 = lane & 15, quad = lane >> 4;
  int wr = wave >> 1, wc = wave & 1;
  int m0 = blockIdx.x * 128;
  int n0 = blockIdx.y * 128;

  // staging source pointers: round r covers rows [r*64 + wave*16, +16)
  int srow = wave * 16 + (lane >> 2);       // 0..63
  int scol = (lane & 3) * 8;                // 0,8,16,24
  const bf16* Asrc = A + (size_t)(m0 + srow) * K + scol;
  const bf16* Bsrc = Bm + (size_t)(n0 + srow) * K + scol;
  bf16* AdstW = As + (size_t)wave * 512;    // wave-uniform LDS base (elements)
  bf16* BdstW = Bs + (size_t)wave * 512;

  f32x4 acc[4][4] = {};
  for (int k0 = 0; k0 < K; k0 += 32) {
#pragma unroll
    for (int r = 0; r < 2; r++) {
      g2lds16(Asrc + (size_t)(r * 64) * K + k0, AdstW + r * 2048);
      g2lds16(Bsrc + (size_t)(r * 64) * K + k0, BdstW + r * 2048);
    }
    __syncthreads();   // compiler emits vmcnt(0) drain before s_barrier

    bf16x8 a[4], b[4];
#pragma unroll
    for (int mi = 0; mi < 4; mi++)
      a[mi] = *(const bf16x8*)&As[(wr * 64 + mi * 16 + lane15) * 32 + quad * 8];
#pragma unroll
    for (int ni = 0; ni < 4; ni++)
      b[ni] = *(const bf16x8*)&Bs[(wc * 64 + ni * 16 + lane15) * 32 + quad * 8];
#pragma unroll
    for (int mi = 0; mi < 4; mi++)
#pragma unroll
      for (int ni = 0; ni < 4; ni++)
        acc[mi][ni] = __builtin_amdgcn_mfma_f32_16x16x32_bf16(a[mi], b[ni], acc[mi][ni], 0, 0, 0);
    __syncthreads();
  }

#pragma unroll
  for (int mi = 0; mi < 4; mi++)
#pragma unroll
    for (int ni = 0; ni < 4; ni++) {
      int col = n0 + wc * 64 + ni * 16 + lane15;
      float bv = BIAS ? bias[col] : 0.f;
#pragma unroll
      for (int r = 0; r < 4; r++) {
        int row = m0 + wr * 64 + mi * 16 + quad * 4 + r;
        C[(size_t)row * N + col] = acc[mi][ni][r] + bv;
      }
    }
}

// ---------------- one GRU time step, fused, 4-wave K-split ----------------
// Block = 256 threads (4 waves). Block computes a 16(b) x 16(i) patch for all
// 3 gates; wave w handles K-range [w*256, w*256+256). Partials reduced in LDS.
__global__ __launch_bounds__(256) void gru_step(const bf16* __restrict__ hbf_p,
                                                const float* __restrict__ h32_p,
                                                const bf16* __restrict__ Whh,   // [3H,H] bf16
                                                const float* __restrict__ bhh,  // [3H]
                                                const float* __restrict__ xp,   // [BT,3H]
                                                float* __restrict__ h32_n,
                                                bf16* __restrict__ hbf_n,
                                                bf16* __restrict__ y,           // [BT,H] bf16
                                                float* __restrict__ finals,
                                                int t) {
  __shared__ float part[3][4][256];
  int tid = threadIdx.x;
  int wave = tid >> 6, lane = tid & 63;
  int lane15 = lane & 15, quad = lane >> 4;
  int i0 = blockIdx.x * 16, b0 = blockIdx.y * 16;
  int kbase = wave * 256;

  const bf16* Ap = hbf_p + (size_t)(b0 + lane15) * Hdim + kbase + quad * 8;
  const bf16* Br = Whh + (size_t)(0 * Hdim + i0 + lane15) * Hdim + kbase + quad * 8;
  const bf16* Bz = Whh + (size_t)(1 * Hdim + i0 + lane15) * Hdim + kbase + quad * 8;
  const bf16* Bn = Whh + (size_t)(2 * Hdim + i0 + lane15) * Hdim + kbase + quad * 8;

  f32x4 ar = {}, az = {}, an = {};
#pragma unroll
  for (int k0 = 0; k0 < 256; k0 += 32) {
    bf16x8 a  = *(const bf16x8*)(Ap + k0);
    bf16x8 br = *(const bf16x8*)(Br + k0);
    bf16x8 bz = *(const bf16x8*)(Bz + k0);
    bf16x8 bn = *(const bf16x8*)(Bn + k0);
    ar = __builtin_amdgcn_mfma_f32_16x16x32_bf16(a, br, ar, 0, 0, 0);
    az = __builtin_amdgcn_mfma_f32_16x16x32_bf16(a, bz, az, 0, 0, 0);
    an = __builtin_amdgcn_mfma_f32_16x16x32_bf16(a, bn, an, 0, 0, 0);
  }
#pragma unroll
  for (int r = 0; r < 4; r++) {
    int idx = (quad * 4 + r) * 16 + lane15;   // row=quad*4+r, col=lane15
    part[0][wave][idx] = ar[r];
    part[1][wave][idx] = az[r];
    part[2][wave][idx] = an[r];
  }
  __syncthreads();

  // one thread per (b_local, i_local) output element
  int b_local = tid >> 4, i_local = tid & 15;
  float hr = part[0][0][tid] + part[0][1][tid] + part[0][2][tid] + part[0][3][tid];
  float hz = part[1][0][tid] + part[1][1][tid] + part[1][2][tid] + part[1][3][tid];
  float hn = part[2][0][tid] + part[2][1][tid] + part[2][2][tid] + part[2][3][tid];
  int i = i0 + i_local, b = b0 + b_local;
  hr += bhh[i]; hz += bhh[Hdim + i]; hn += bhh[2 * Hdim + i];
  size_t m = (size_t)b * Tdim + t;
  float xr = xp[m * G3H + i];
  float xz = xp[m * G3H + Hdim + i];
  float xn = xp[m * G3H + 2 * Hdim + i];
  float rg = 1.f / (1.f + __expf(-(xr + hr)));
  float zg = 1.f / (1.f + __expf(-(xz + hz)));
  float ng = tanhf(xn + rg * hn);
  float hold = h32_p[(size_t)b * Hdim + i];
  float hnew = (1.f - zg) * ng + zg * hold;
  h32_n[(size_t)b * Hdim + i] = hnew;
  hbf_n[(size_t)b * Hdim + i] = (bf16)hnew;
  y[m * Hdim + i] = (bf16)hnew;
  if (t == Tdim - 1) finals[(size_t)b * Hdim + i] = hnew;
}

// ---------------- in-place log_softmax over V per row (float4) ----------------
__global__ __launch_bounds__(256) void logsoftmax(float* __restrict__ out) {
  __shared__ float sm[256], ss[256];
  int row = blockIdx.x;
  f32x4* x = (f32x4*)(out + (size_t)row * Vdim);
  const int n4 = Vdim / 4;  // 8000
  float m = -1e30f, s = 0.f;
  for (int j = threadIdx.x; j < n4; j += 256) {
    f32x4 v = x[j];
    float vm = fmaxf(fmaxf(v[0], v[1]), fmaxf(v[2], v[3]));
    float nm = fmaxf(m, vm);
    s = s * __expf(m - nm) + __expf(v[0] - nm) + __expf(v[1] - nm)
                           + __expf(v[2] - nm) + __expf(v[3] - nm);
    m = nm;
  }
  sm[threadIdx.x] = m; ss[threadIdx.x] = s;
  __syncthreads();
  for (int off = 128; off; off >>= 1) {
    if (threadIdx.x < off) {
      float m1 = sm[threadIdx.x], s1 = ss[threadIdx.x];
      float m2 = sm[threadIdx.x + off], s2 = ss[threadIdx.x + off];
      float mm = fmaxf(m1, m2);
      sm[threadIdx.x] = mm;
      ss[threadIdx.x] = s1 * __expf(m1 - mm) + s2 * __expf(m2 - mm);
    }
    __syncthreads();
  }
  float lse = sm[0] + logf(ss[0]);
  for (int j = threadIdx.x; j < n4; j += 256) {
    f32x4 v = x[j];
    v[0] -= lse; v[1] -= lse; v[2] -= lse; v[3] -= lse;
    x[j] = v;
  }
}

extern "C" void kernel_launch(void* const* d_in, const int* in_sizes, int n_in,
                              void* d_out, int out_size, void* d_ws, size_t ws_size,
                              hipStream_t stream) {
  const float* enc_hidden = (const float*)d_in[1];
  const int*   target     = (const int*)d_in[2];
  const float* emb        = (const float*)d_in[3];
  const float* W_ih       = (const float*)d_in[4];
  const float* W_hh       = (const float*)d_in[5];
  const float* b_ih       = (const float*)d_in[6];
  const float* b_hh       = (const float*)d_in[7];
  const float* W_out      = (const float*)d_in[8];
  const float* b_out      = (const float*)d_in[9];

  float* out = (float*)d_out;                       // [BT, V] logits/logprobs
  float* finals = out + (size_t)BT * Vdim;          // [L, B, H]

  uint8_t* wsp = (uint8_t*)d_ws;
  auto alloc = [&](size_t bytes) {
    uint8_t* p = wsp;
    wsp += (bytes + 255) & ~(size_t)255;
    return p;
  };
  bf16* wih_bf  = (bf16*)alloc((size_t)LAYERS * G3H * Hdim * 2);
  bf16* whh_bf  = (bf16*)alloc((size_t)LAYERS * G3H * Hdim * 2);
  bf16* wout_bf = (bf16*)alloc((size_t)Vdim * Hdim * 2);
  bf16* xA      = (bf16*)alloc((size_t)BT * Hdim * 2);
  bf16* xB      = (bf16*)alloc((size_t)BT * Hdim * 2);
  float* xp     = (float*)alloc((size_t)BT * G3H * 4);
  float* h32a   = (float*)alloc((size_t)Bdim * Hdim * 4);
  float* h32b   = (float*)alloc((size_t)Bdim * Hdim * 4);
  bf16* hbfa    = (bf16*)alloc((size_t)Bdim * Hdim * 2);
  bf16* hbfb    = (bf16*)alloc((size_t)Bdim * Hdim * 2);
  float* h32[2] = {h32a, h32b};
  bf16*  hbf[2] = {hbfa, hbfb};

  {
    int n4 = LAYERS * G3H * Hdim / 4;
    cvt_f32_bf16<<<(n4 + 255) / 256, 256, 0, stream>>>(W_ih, wih_bf, n4);
    cvt_f32_bf16<<<(n4 + 255) / 256, 256, 0, stream>>>(W_hh, whh_bf, n4);
    int m4 = Vdim * Hdim / 4;
    cvt_f32_bf16<<<(m4 + 255) / 256, 256, 0, stream>>>(W_out, wout_bf, m4);
  }

  embed_relu<<<BT, 256, 0, stream>>>(target, emb, xA);

  bf16* xin = xA;
  bf16* xout_ = xB;
  for (int l = 0; l < LAYERS; l++) {
    hinit<<<64, 256, 0, stream>>>(enc_hidden + (size_t)l * Bdim * Hdim, h32[0], hbf[0]);
    // xp = x @ W_ih[l]^T + b_ih[l]  : M=2048, N=3072, K=1024
    dim3 g1(BT / 128, G3H / 128);
    gemm_lds<true><<<g1, 256, 0, stream>>>(xin, wih_bf + (size_t)l * G3H * Hdim,
                                           b_ih + (size_t)l * G3H, xp, BT, G3H, Hdim);
    for (int t = 0; t < Tdim; t++) {
      int p = t & 1;
      gru_step<<<dim3(Hdim / 16, Bdim / 16), 256, 0, stream>>>(
          hbf[p], h32[p], whh_bf + (size_t)l * G3H * Hdim, b_hh + (size_t)l * G3H,
          xp, h32[p ^ 1], hbf[p ^ 1], xout_, finals + (size_t)l * Bdim * Hdim, t);
    }
    bf16* tmp = xin; xin = xout_; xout_ = tmp;
  }

  // logits = x @ W_out^T + b_out : M=2048, N=32000, K=1024 -> d_out
  dim3 g2(BT / 128, Vdim / 128);
  gemm_lds<true><<<g2, 256, 0, stream>>>(xin, wout_bf, b_out, out, BT, Vdim, Hdim);

  logsoftmax<<<BT, 256, 0, stream>>>(out);
}